// Round 10
// baseline (554.872 us; speedup 1.0000x reference)
//
#include <hip/hip_runtime.h>
#include <math.h>

#define NNODES 50000
#define NEDGES 400000
#define E2 (NEDGES + NNODES)   // with self loops
#define HC 256                 // heads*channels per side
#define NOUT 512               // concat [Wl | Wr]
#define NF (NOUT / 16)         // 32 n-fragments
#define BN_SCALE 0.9999950000374997f   // 1/sqrt(1+1e-5)
#define LOG2E 1.4426950408889634f
#define SCAN_B ((NNODES + 255) / 256)  // 196
#define GEMM_B ((NNODES + 63) / 64)    // 782
#define HIST_B ((E2 + 255) / 256)      // 1758

typedef unsigned short ushortx8 __attribute__((ext_vector_type(8)));
typedef __bf16 bf16x8 __attribute__((ext_vector_type(8)));
typedef float f32x4 __attribute__((ext_vector_type(4)));
typedef float f32x2 __attribute__((ext_vector_type(2)));

__device__ inline unsigned short f2bf(float f) {
    unsigned u = __float_as_uint(f);
    u += 0x7fff + ((u >> 16) & 1);   // round to nearest even
    return (unsigned short)(u >> 16);
}

// VALU cross-lane add via DPP (within 16-lane row)
template <int CTRL>
__device__ __forceinline__ float dpp_add(float x) {
    int y = __builtin_amdgcn_update_dpp(0, __float_as_int(x), CTRL, 0xF, 0xF, true);
    return x + __int_as_float(y);
}
__device__ __forceinline__ float row16_sum(float x) {
    x = dpp_add<0xB1>(x);    // xor 1
    x = dpp_add<0x4E>(x);    // xor 2
    x = dpp_add<0x141>(x);   // row_half_mirror (xor 4)
    x = dpp_add<0x140>(x);   // row_mirror (xor 8)
    return x;
}

// ---------------- packing ----------------
#define B1_N (128 * NOUT)           // 65,536
#define B2_N (256 * NOUT)           // 131,072
#define PACK_B ((B1_N + B2_N + 255) / 256)

__device__ __forceinline__ void prep_one(const float* __restrict__ Wl,
                                         const float* __restrict__ Wr,
                                         unsigned short* __restrict__ Bf, int id) {
    // Bf[(((kb*NF + nf)*64 + lane)*8 + j)] = B[kb*32 + (lane>>4)*8 + j][nf*16 + (lane&15)]
    int j    = id & 7;
    int lane = (id >> 3) & 63;
    int nf   = (id >> 9) & (NF - 1);
    int kb   = id >> 14;
    int k = kb * 32 + (lane >> 4) * 8 + j;
    int c = nf * 16 + (lane & 15);
    float v = (c < 256) ? Wl[k * 256 + c] : Wr[k * 256 + (c - 256)];
    Bf[id] = f2bf(v);
}

// K1: pack W1/W2 fragment layout || dst histogram
__global__ __launch_bounds__(256) void k1_pack_hist(
        const float* __restrict__ W1l, const float* __restrict__ W1r,
        const float* __restrict__ W2l, const float* __restrict__ W2r,
        unsigned short* __restrict__ Bf1, unsigned short* __restrict__ Bf2,
        const int* __restrict__ ei, int* __restrict__ deg) {
    int bid = blockIdx.x;
    if (bid < PACK_B) {
        int id = bid * 256 + threadIdx.x;
        if (id < B1_N) {
            prep_one(W1l, W1r, Bf1, id);
        } else if (id < B1_N + B2_N) {
            prep_one(W2l, W2r, Bf2, id - B1_N);
        }
    } else {
        int i = (bid - PACK_B) * 256 + threadIdx.x;
        if (i < E2) {
            int d = (i < NEDGES) ? ei[NEDGES + i] : i - NEDGES;
            atomicAdd(&deg[d], 1);
        }
    }
}

// ---------------- GEMM body: C[M][512] = A[M][K] * B[K][512], C in bf16 ----------------
template <bool AF32>
__device__ __forceinline__ void gemm_body(int bx, int tid,
        const void* __restrict__ Av, const unsigned short* __restrict__ Bf,
        unsigned short* __restrict__ C, int M, int K) {
    const int lane = tid & 63;
    const int w    = tid >> 6;          // col panel 0..3
    const int row0 = bx * 64;
    const int col0 = w * 128;
    const int lr = lane & 15, lg = lane >> 4;

    f32x4 acc[4][8] = {};
    const int nkb = K >> 5;
    for (int kb = 0; kb < nkb; ++kb) {
        bf16x8 af[4], bfr[8];
        const int kcol = kb * 32 + lg * 8;
#pragma unroll
        for (int i = 0; i < 4; ++i) {
            int r = row0 + i * 16 + lr;
            if constexpr (AF32) {
                const float* Af = (const float*)Av;
                f32x4 a0 = {}, a1 = {};
                if (r < M) {
                    a0 = *reinterpret_cast<const f32x4*>(Af + (size_t)r * K + kcol);
                    a1 = *reinterpret_cast<const f32x4*>(Af + (size_t)r * K + kcol + 4);
                }
                bf16x8 t;
#pragma unroll
                for (int q = 0; q < 4; ++q) { t[q] = (__bf16)a0[q]; t[4 + q] = (__bf16)a1[q]; }
                af[i] = t;
            } else {
                const unsigned short* Ab = (const unsigned short*)Av;
                ushortx8 av = {};
                if (r < M)
                    av = *reinterpret_cast<const ushortx8*>(Ab + (size_t)r * K + kcol);
                af[i] = __builtin_bit_cast(bf16x8, av);
            }
        }
#pragma unroll
        for (int j = 0; j < 8; ++j) {
            int nf = (col0 >> 4) + j;
            ushortx8 bv = *reinterpret_cast<const ushortx8*>(
                Bf + (((size_t)(kb * NF + nf) * 64 + lane) << 3));
            bfr[j] = __builtin_bit_cast(bf16x8, bv);
        }
#pragma unroll
        for (int i = 0; i < 4; ++i)
#pragma unroll
            for (int j = 0; j < 8; ++j)
                acc[i][j] = __builtin_amdgcn_mfma_f32_16x16x32_bf16(
                    af[i], bfr[j], acc[i][j], 0, 0, 0);
    }
#pragma unroll
    for (int i = 0; i < 4; ++i) {
#pragma unroll
        for (int r = 0; r < 4; ++r) {
            int row = row0 + i * 16 + lg * 4 + r;
            if (row < M) {
#pragma unroll
                for (int j = 0; j < 8; ++j)
                    C[(size_t)row * NOUT + col0 + j * 16 + lr] = f2bf(acc[i][j][r]);
            }
        }
    }
}

// K2: gemm layer-1 (f32 A) || scan1 (+ degree-bucket histogram)
__global__ __launch_bounds__(256) void k2_gemm1_scan1(
        const float* __restrict__ A, const unsigned short* __restrict__ Bf,
        unsigned short* __restrict__ C, int M, int K,
        const int* __restrict__ deg, int* __restrict__ rowptr, int* __restrict__ bsum,
        int* __restrict__ dhist) {
    __shared__ int buf[256];
    if (blockIdx.x < GEMM_B) {
        gemm_body<true>(blockIdx.x, threadIdx.x, A, Bf, C, M, K);
    } else {
        int bx = blockIdx.x - GEMM_B;
        int t = threadIdx.x;
        int i = bx * 256 + t;
        int v = (i < NNODES) ? deg[i] : 0;
        if (i < NNODES) {
            int d = v > 63 ? 63 : v;
            atomicAdd(&dhist[d], 1);
        }
        buf[t] = v;
        __syncthreads();
        for (int off = 1; off < 256; off <<= 1) {
            int u = (t >= off) ? buf[t - off] : 0;
            __syncthreads();
            buf[t] += u;
            __syncthreads();
        }
        if (i < NNODES) rowptr[i] = buf[t] - v;
        if (t == 255) bsum[bx] = buf[255];
    }
}

// K3: bsum prefix + add-back; also counting-sort nodes by degree into perm
__global__ __launch_bounds__(256) void k3_scan23(
        const int* __restrict__ bsum, const int* __restrict__ deg,
        int* __restrict__ rowptr, int* __restrict__ cursor,
        const int* __restrict__ dhist, int* __restrict__ dcur,
        int* __restrict__ perm) {
    __shared__ int sbuf[256];
    __shared__ int dpre[64];
    int t = threadIdx.x;
    int v = (t < (int)blockIdx.x && t < SCAN_B) ? bsum[t] : 0;
    sbuf[t] = v;
    if (t < 64) {
        int s = 0;
        for (int k = 0; k < t; ++k) s += dhist[k];
        dpre[t] = s;
    }
    __syncthreads();
    for (int off = 128; off; off >>= 1) {
        if (t < off) sbuf[t] += sbuf[t + off];
        __syncthreads();
    }
    int base = sbuf[0];
    int i = blockIdx.x * 256 + t;
    if (i < NNODES) {
        int r = rowptr[i] + base;
        rowptr[i] = r;
        cursor[i] = r;
        int d = deg[i]; if (d > 63) d = 63;
        int slot = dpre[d] + atomicAdd(&dcur[d], 1);
        perm[slot] = i;
    }
    if (blockIdx.x == 0 && t == 0) rowptr[NNODES] = E2;
}

// K4: scatter src into dst-grouped order; stores PRE-SCALED row offset (s*NOUT)
__global__ __launch_bounds__(256) void k4_scatter(
        const int* __restrict__ ei, int* __restrict__ cursor, int* __restrict__ csr_src) {
    int i = blockIdx.x * blockDim.x + threadIdx.x;
    if (i >= E2) return;
    int s, d;
    if (i < NEDGES) { s = ei[i]; d = ei[NEDGES + i]; }
    else            { s = i - NEDGES; d = s; }
    int slot = atomicAdd(&cursor[d], 1);
    csr_src[slot] = s * NOUT;
}

// standalone GEMM (layer 2, bf16 A)
__global__ __launch_bounds__(256) void gemm_mfma(
        const unsigned short* __restrict__ A, const unsigned short* __restrict__ Bf,
        unsigned short* __restrict__ C, int M, int K) {
    gemm_body<false>(blockIdx.x, threadIdx.x, A, Bf, C, M, K);
}

// ---------------- fused per-node GAT: degree-sorted waves, DPP reduce, exp2 ----------------
// xlr[N][512] bf16: cols 0..255 = xl (messages), 256..511 = xr (dest)
// csr_src holds pre-scaled row offsets (src*NOUT); perm = degree-sorted node order.
template <int LAYER>
__global__ __launch_bounds__(256) void gat_node(
        const unsigned short* __restrict__ xlr,
        const float* __restrict__ att, const int* __restrict__ rowptr,
        const int* __restrict__ csr_src, const int* __restrict__ perm,
        const float* __restrict__ bias, const float* __restrict__ g,
        const float* __restrict__ be,
        const float* __restrict__ fcW, const float* __restrict__ fcb,
        void* __restrict__ outv) {
    int slot = (blockIdx.x * blockDim.x + threadIdx.x) >> 6;
    int lane = threadIdx.x & 63;
    if (slot >= NNODES) return;
    const int wid = perm[slot];   // degree-sorted node id

    f32x2 xb01, xb23, at01, at23;
    {
        uint2 wv = *reinterpret_cast<const uint2*>(xlr + (size_t)wid * NOUT + 256 + lane * 4);
        xb01.x = __uint_as_float(wv.x << 16);
        xb01.y = __uint_as_float(wv.x & 0xffff0000u);
        xb23.x = __uint_as_float(wv.y << 16);
        xb23.y = __uint_as_float(wv.y & 0xffff0000u);
        float4 a = *reinterpret_cast<const float4*>(att + lane * 4);
        at01.x = a.x * LOG2E; at01.y = a.y * LOG2E;   // pre-scale: exp(e) == exp2(e*log2e)
        at23.x = a.z * LOG2E; at23.y = a.w * LOG2E;
    }
    const int beg = rowptr[wid];
    const int end = rowptr[wid + 1];
    const unsigned short* __restrict__ xbase = xlr + lane * 4;

    float den = 0.f;
    f32x2 ac01 = {0.f, 0.f}, ac23 = {0.f, 0.f};

    auto edge = [&](uint2 wv) {
        f32x2 xv01, xv23;
        xv01.x = __uint_as_float(wv.x << 16);
        xv01.y = __uint_as_float(wv.x & 0xffff0000u);
        xv23.x = __uint_as_float(wv.y << 16);
        xv23.y = __uint_as_float(wv.y & 0xffff0000u);
        f32x2 v01 = xv01 + xb01;
        f32x2 v23 = xv23 + xb23;
        v01 = __builtin_elementwise_max(v01, v01 * 0.2f);   // leaky_relu
        v23 = __builtin_elementwise_max(v23, v23 * 0.2f);
        f32x2 d2 = v01 * at01 + v23 * at23;
        float part = row16_sum(d2.x + d2.y);   // per-head logit (already ×log2e)
        float p = exp2f(part);                  // native v_exp_f32
        den += p;
        ac01 += p * xv01;
        ac23 += p * xv23;
    };

    int j = beg;
    for (; j + 4 <= end; j += 4) {
        int s0 = csr_src[j], s1 = csr_src[j + 1], s2 = csr_src[j + 2], s3 = csr_src[j + 3];
        uint2 w0 = *reinterpret_cast<const uint2*>(xbase + (size_t)(unsigned)s0);
        uint2 w1 = *reinterpret_cast<const uint2*>(xbase + (size_t)(unsigned)s1);
        uint2 w2 = *reinterpret_cast<const uint2*>(xbase + (size_t)(unsigned)s2);
        uint2 w3 = *reinterpret_cast<const uint2*>(xbase + (size_t)(unsigned)s3);
        edge(w0); edge(w1); edge(w2); edge(w3);
    }
    for (; j < end; ++j) {
        int s0 = csr_src[j];
        uint2 w0 = *reinterpret_cast<const uint2*>(xbase + (size_t)(unsigned)s0);
        edge(w0);
    }

    float inv = 1.f / (den + 1e-16f);
    float ax = ac01.x * inv, ay = ac01.y * inv, az = ac23.x * inv, aw = ac23.y * inv;

    if (LAYER == 1) {
        int c0 = lane * 4;
        float o0 = (ax + bias[c0 + 0]) * BN_SCALE * g[c0 + 0] + be[c0 + 0];
        float o1 = (ay + bias[c0 + 1]) * BN_SCALE * g[c0 + 1] + be[c0 + 1];
        float o2 = (az + bias[c0 + 2]) * BN_SCALE * g[c0 + 2] + be[c0 + 2];
        float o3 = (aw + bias[c0 + 3]) * BN_SCALE * g[c0 + 3] + be[c0 + 3];
        o0 = o0 > 0.f ? o0 : expm1f(o0);
        o1 = o1 > 0.f ? o1 : expm1f(o1);
        o2 = o2 > 0.f ? o2 : expm1f(o2);
        o3 = o3 > 0.f ? o3 : expm1f(o3);
        ushort4 o = { f2bf(o0), f2bf(o1), f2bf(o2), f2bf(o3) };
        *reinterpret_cast<ushort4*>((unsigned short*)outv + (size_t)wid * HC + lane * 4) = o;
    } else {
        // mean over heads: lanes l, l^16, l^32, l^48 hold the same channels
#pragma unroll
        for (int off = 16; off < 64; off <<= 1) {
            ax += __shfl_xor(ax, off);
            ay += __shfl_xor(ay, off);
            az += __shfl_xor(az, off);
            aw += __shfl_xor(aw, off);
        }
        int c0 = (lane & 15) * 4;
        float v0 = (ax * 0.25f + bias[c0 + 0]) * BN_SCALE * g[c0 + 0] + be[c0 + 0];
        float v1 = (ay * 0.25f + bias[c0 + 1]) * BN_SCALE * g[c0 + 1] + be[c0 + 1];
        float v2 = (az * 0.25f + bias[c0 + 2]) * BN_SCALE * g[c0 + 2] + be[c0 + 2];
        float v3 = (aw * 0.25f + bias[c0 + 3]) * BN_SCALE * g[c0 + 3] + be[c0 + 3];
        v0 = v0 > 0.f ? v0 : expm1f(v0);
        v1 = v1 > 0.f ? v1 : expm1f(v1);
        v2 = v2 > 0.f ? v2 : expm1f(v2);
        v3 = v3 > 0.f ? v3 : expm1f(v3);
        float dot = v0 * fcW[c0] + v1 * fcW[c0 + 1] + v2 * fcW[c0 + 2] + v3 * fcW[c0 + 3];
        dot = row16_sum(dot);
        if (lane == 0) ((float*)outv)[wid] = 1.f / (1.f + __expf(-(dot + fcb[0])));
    }
}

extern "C" void kernel_launch(void* const* d_in, const int* in_sizes, int n_in,
                              void* d_out, int out_size, void* d_ws, size_t ws_size,
                              hipStream_t stream) {
    const float* x    = (const float*)d_in[0];
    const int*   ei   = (const int*)d_in[1];
    const float* W1l  = (const float*)d_in[2];
    const float* W1r  = (const float*)d_in[3];
    const float* att1 = (const float*)d_in[4];
    const float* b1   = (const float*)d_in[5];
    const float* g1   = (const float*)d_in[6];
    const float* be1  = (const float*)d_in[7];
    const float* W2l  = (const float*)d_in[8];
    const float* W2r  = (const float*)d_in[9];
    const float* att2 = (const float*)d_in[10];
    const float* b2   = (const float*)d_in[11];
    const float* g2   = (const float*)d_in[12];
    const float* be2  = (const float*)d_in[13];
    const float* fcW  = (const float*)d_in[14];
    const float* fcb  = (const float*)d_in[15];
    float* out = (float*)d_out;

    // workspace carve-up (bf16 = ushort)
    unsigned short* xlr   = (unsigned short*)d_ws;                 // N*512
    unsigned short* h1_bf = xlr + (size_t)NNODES * NOUT;           // N*256
    unsigned short* Bf1   = h1_bf + (size_t)NNODES * 256;          // 128*512
    unsigned short* Bf2   = Bf1 + 128 * NOUT;                      // 256*512
    int* csr_src = (int*)(Bf2 + 256 * NOUT);                       // E2
    int* deg     = csr_src + E2;                                   // N  (also over-read pad)
    int* dhist   = deg + NNODES;                                   // 64
    int* dcur    = dhist + 64;                                     // 64
    int* rowptr  = dcur + 64;                                      // N+1
    int* cursor  = rowptr + NNODES + 1;                            // N
    int* bsum    = cursor + NNODES;                                // SCAN_B
    int* perm    = bsum + SCAN_B;                                  // N

    const int nodeBlocks = (NNODES * 64 + 255) / 256;

    // zero deg + dhist + dcur in one memset (contiguous)
    hipMemsetAsync(deg, 0, (NNODES + 128) * sizeof(int), stream);

    // K1: pack (W1, W2) || dst histogram
    k1_pack_hist<<<PACK_B + HIST_B, 256, 0, stream>>>(
        W1l, W1r, W2l, W2r, Bf1, Bf2, ei, deg);

    // K2: gemm layer-1 (direct f32 x) || scan1 + degree-bucket hist
    k2_gemm1_scan1<<<GEMM_B + SCAN_B, 256, 0, stream>>>(
        x, Bf1, xlr, NNODES, 128, deg, rowptr, bsum, dhist);

    // K3: bsum prefix + add-back + counting-sort perm
    k3_scan23<<<SCAN_B, 256, 0, stream>>>(bsum, deg, rowptr, cursor, dhist, dcur, perm);

    // K4: scatter into CSR (pre-scaled offsets)
    k4_scatter<<<HIST_B, 256, 0, stream>>>(ei, cursor, csr_src);

    // layer 1 aggregation + epilogue
    gat_node<1><<<nodeBlocks, 256, 0, stream>>>(xlr, att1, rowptr, csr_src, perm,
                                                b1, g1, be1, nullptr, nullptr, h1_bf);

    // layer 2
    gemm_mfma<<<GEMM_B, 256, 0, stream>>>(h1_bf, Bf2, xlr, NNODES, 256);
    gat_node<2><<<nodeBlocks, 256, 0, stream>>>(xlr, att2, rowptr, csr_src, perm,
                                                b2, g2, be2, fcW, fcb, out);
}

// Round 12
// 217.313 us; speedup vs baseline: 2.5533x; 2.5533x over previous
//
#include <hip/hip_runtime.h>
#include <math.h>

#define NNODES 50000
#define NEDGES 400000
#define E2 (NEDGES + NNODES)   // with self loops
#define HC 256                 // heads*channels per side
#define NOUT 512               // concat [Wl | Wr]
#define NF (NOUT / 16)         // 32 n-fragments
#define BN_SCALE 0.9999950000374997f   // 1/sqrt(1+1e-5)
#define LOG2E 1.4426950408889634f
#define SCAN_B ((NNODES + 255) / 256)  // 196
#define GEMM_B ((NNODES + 63) / 64)    // 782
#define HIST_B ((E2 + 255) / 256)      // 1758

typedef unsigned short ushortx8 __attribute__((ext_vector_type(8)));
typedef __bf16 bf16x8 __attribute__((ext_vector_type(8)));
typedef float f32x4 __attribute__((ext_vector_type(4)));
typedef float f32x2 __attribute__((ext_vector_type(2)));

__device__ inline unsigned short f2bf(float f) {
    unsigned u = __float_as_uint(f);
    u += 0x7fff + ((u >> 16) & 1);   // round to nearest even
    return (unsigned short)(u >> 16);
}

// VALU cross-lane add via DPP builtin (compiler handles DPP read-after-write
// wait states; inline-asm DPP does NOT — caused round-11 corruption).
template <int CTRL>
__device__ __forceinline__ float dpp_add(float x) {
    int y = __builtin_amdgcn_update_dpp(0, __float_as_int(x), CTRL, 0xF, 0xF, true);
    return x + __int_as_float(y);
}
__device__ __forceinline__ float row16_sum(float x) {
    x = dpp_add<0xB1>(x);    // xor 1 (quad_perm [1,0,3,2])
    x = dpp_add<0x4E>(x);    // xor 2 (quad_perm [2,3,0,1])
    x = dpp_add<0x141>(x);   // row_half_mirror (xor 4)
    x = dpp_add<0x140>(x);   // row_mirror (xor 8)
    return x;
}

// ---------------- packing ----------------
#define B1_N (128 * NOUT)           // 65,536
#define B2_N (256 * NOUT)           // 131,072
#define PACK_B ((B1_N + B2_N + 255) / 256)

__device__ __forceinline__ void prep_one(const float* __restrict__ Wl,
                                         const float* __restrict__ Wr,
                                         unsigned short* __restrict__ Bf, int id) {
    // Bf[(((kb*NF + nf)*64 + lane)*8 + j)] = B[kb*32 + (lane>>4)*8 + j][nf*16 + (lane&15)]
    int j    = id & 7;
    int lane = (id >> 3) & 63;
    int nf   = (id >> 9) & (NF - 1);
    int kb   = id >> 14;
    int k = kb * 32 + (lane >> 4) * 8 + j;
    int c = nf * 16 + (lane & 15);
    float v = (c < 256) ? Wl[k * 256 + c] : Wr[k * 256 + (c - 256)];
    Bf[id] = f2bf(v);
}

// K1: pack W1/W2 fragment layout || dst histogram
__global__ __launch_bounds__(256) void k1_pack_hist(
        const float* __restrict__ W1l, const float* __restrict__ W1r,
        const float* __restrict__ W2l, const float* __restrict__ W2r,
        unsigned short* __restrict__ Bf1, unsigned short* __restrict__ Bf2,
        const int* __restrict__ ei, int* __restrict__ deg) {
    int bid = blockIdx.x;
    if (bid < PACK_B) {
        int id = bid * 256 + threadIdx.x;
        if (id < B1_N) {
            prep_one(W1l, W1r, Bf1, id);
        } else if (id < B1_N + B2_N) {
            prep_one(W2l, W2r, Bf2, id - B1_N);
        }
    } else {
        int i = (bid - PACK_B) * 256 + threadIdx.x;
        if (i < E2) {
            int d = (i < NEDGES) ? ei[NEDGES + i] : i - NEDGES;
            atomicAdd(&deg[d], 1);
        }
    }
}

// ---------------- GEMM body: C[M][512] = A[M][K] * B[K][512], C in bf16 ----------------
template <bool AF32>
__device__ __forceinline__ void gemm_body(int bx, int tid,
        const void* __restrict__ Av, const unsigned short* __restrict__ Bf,
        unsigned short* __restrict__ C, int M, int K) {
    const int lane = tid & 63;
    const int w    = tid >> 6;          // col panel 0..3
    const int row0 = bx * 64;
    const int col0 = w * 128;
    const int lr = lane & 15, lg = lane >> 4;

    f32x4 acc[4][8] = {};
    const int nkb = K >> 5;
    for (int kb = 0; kb < nkb; ++kb) {
        bf16x8 af[4], bfr[8];
        const int kcol = kb * 32 + lg * 8;
#pragma unroll
        for (int i = 0; i < 4; ++i) {
            int r = row0 + i * 16 + lr;
            if constexpr (AF32) {
                const float* Af = (const float*)Av;
                f32x4 a0 = {}, a1 = {};
                if (r < M) {
                    a0 = *reinterpret_cast<const f32x4*>(Af + (size_t)r * K + kcol);
                    a1 = *reinterpret_cast<const f32x4*>(Af + (size_t)r * K + kcol + 4);
                }
                bf16x8 t;
#pragma unroll
                for (int q = 0; q < 4; ++q) { t[q] = (__bf16)a0[q]; t[4 + q] = (__bf16)a1[q]; }
                af[i] = t;
            } else {
                const unsigned short* Ab = (const unsigned short*)Av;
                ushortx8 av = {};
                if (r < M)
                    av = *reinterpret_cast<const ushortx8*>(Ab + (size_t)r * K + kcol);
                af[i] = __builtin_bit_cast(bf16x8, av);
            }
        }
#pragma unroll
        for (int j = 0; j < 8; ++j) {
            int nf = (col0 >> 4) + j;
            ushortx8 bv = *reinterpret_cast<const ushortx8*>(
                Bf + (((size_t)(kb * NF + nf) * 64 + lane) << 3));
            bfr[j] = __builtin_bit_cast(bf16x8, bv);
        }
#pragma unroll
        for (int i = 0; i < 4; ++i)
#pragma unroll
            for (int j = 0; j < 8; ++j)
                acc[i][j] = __builtin_amdgcn_mfma_f32_16x16x32_bf16(
                    af[i], bfr[j], acc[i][j], 0, 0, 0);
    }
#pragma unroll
    for (int i = 0; i < 4; ++i) {
#pragma unroll
        for (int r = 0; r < 4; ++r) {
            int row = row0 + i * 16 + lg * 4 + r;
            if (row < M) {
#pragma unroll
                for (int j = 0; j < 8; ++j)
                    C[(size_t)row * NOUT + col0 + j * 16 + lr] = f2bf(acc[i][j][r]);
            }
        }
    }
}

// K2: gemm layer-1 (f32 A) || block-local exclusive scan of deg
__global__ __launch_bounds__(256) void k2_gemm1_scan1(
        const float* __restrict__ A, const unsigned short* __restrict__ Bf,
        unsigned short* __restrict__ C, int M, int K,
        const int* __restrict__ deg, int* __restrict__ rowptr, int* __restrict__ bsum) {
    __shared__ int buf[256];
    if (blockIdx.x < GEMM_B) {
        gemm_body<true>(blockIdx.x, threadIdx.x, A, Bf, C, M, K);
    } else {
        int bx = blockIdx.x - GEMM_B;
        int t = threadIdx.x;
        int i = bx * 256 + t;
        int v = (i < NNODES) ? deg[i] : 0;
        buf[t] = v;
        __syncthreads();
        for (int off = 1; off < 256; off <<= 1) {
            int u = (t >= off) ? buf[t - off] : 0;
            __syncthreads();
            buf[t] += u;
            __syncthreads();
        }
        if (i < NNODES) rowptr[i] = buf[t] - v;
        if (t == 255) bsum[bx] = buf[255];
    }
}

// K3: per-block recompute of bsum prefix + add-back
__global__ __launch_bounds__(256) void k3_scan23(
        const int* __restrict__ bsum, int* __restrict__ rowptr, int* __restrict__ cursor) {
    __shared__ int sbuf[256];
    int t = threadIdx.x;
    int v = (t < (int)blockIdx.x && t < SCAN_B) ? bsum[t] : 0;
    sbuf[t] = v;
    __syncthreads();
    for (int off = 128; off; off >>= 1) {
        if (t < off) sbuf[t] += sbuf[t + off];
        __syncthreads();
    }
    int base = sbuf[0];
    int i = blockIdx.x * 256 + t;
    if (i < NNODES) {
        int r = rowptr[i] + base;
        rowptr[i] = r;
        cursor[i] = r;
    }
    if (blockIdx.x == 0 && t == 0) rowptr[NNODES] = E2;
}

// K4: scatter src into dst-grouped order; stores PRE-SCALED row offset (s*NOUT)
__global__ __launch_bounds__(256) void k4_scatter(
        const int* __restrict__ ei, int* __restrict__ cursor, int* __restrict__ csr_src) {
    int i = blockIdx.x * blockDim.x + threadIdx.x;
    if (i >= E2) return;
    int s, d;
    if (i < NEDGES) { s = ei[i]; d = ei[NEDGES + i]; }
    else            { s = i - NEDGES; d = s; }
    int slot = atomicAdd(&cursor[d], 1);
    csr_src[slot] = s * NOUT;
}

// standalone GEMM (layer 2, bf16 A)
__global__ __launch_bounds__(256) void gemm_mfma(
        const unsigned short* __restrict__ A, const unsigned short* __restrict__ Bf,
        unsigned short* __restrict__ C, int M, int K) {
    gemm_body<false>(blockIdx.x, threadIdx.x, A, Bf, C, M, K);
}

// ---------------- fused per-node GAT: 4 ch/lane, DPP reduce, exp2, 4-edge unroll ----------
// xlr[N][512] bf16: cols 0..255 = xl (messages), 256..511 = xr (dest)
// csr_src holds pre-scaled row offsets (src*NOUT).
template <int LAYER>
__global__ __launch_bounds__(256) void gat_node(
        const unsigned short* __restrict__ xlr,
        const float* __restrict__ att, const int* __restrict__ rowptr,
        const int* __restrict__ csr_src,
        const float* __restrict__ bias, const float* __restrict__ g,
        const float* __restrict__ be,
        const float* __restrict__ fcW, const float* __restrict__ fcb,
        void* __restrict__ outv) {
    int wid  = (blockIdx.x * blockDim.x + threadIdx.x) >> 6;   // node id
    int lane = threadIdx.x & 63;
    if (wid >= NNODES) return;

    f32x2 xb01, xb23, at01, at23;
    {
        uint2 wv = *reinterpret_cast<const uint2*>(xlr + (size_t)wid * NOUT + 256 + lane * 4);
        xb01.x = __uint_as_float(wv.x << 16);
        xb01.y = __uint_as_float(wv.x & 0xffff0000u);
        xb23.x = __uint_as_float(wv.y << 16);
        xb23.y = __uint_as_float(wv.y & 0xffff0000u);
        float4 a = *reinterpret_cast<const float4*>(att + lane * 4);
        at01.x = a.x * LOG2E; at01.y = a.y * LOG2E;   // exp(e) == exp2(e*log2e)
        at23.x = a.z * LOG2E; at23.y = a.w * LOG2E;
    }
    const int beg = rowptr[wid];
    const int end = rowptr[wid + 1];
    const unsigned short* __restrict__ xbase = xlr + lane * 4;

    float den = 0.f;
    f32x2 ac01 = {0.f, 0.f}, ac23 = {0.f, 0.f};

    auto edge = [&](uint2 wv) {
        f32x2 xv01, xv23;
        xv01.x = __uint_as_float(wv.x << 16);
        xv01.y = __uint_as_float(wv.x & 0xffff0000u);
        xv23.x = __uint_as_float(wv.y << 16);
        xv23.y = __uint_as_float(wv.y & 0xffff0000u);
        f32x2 v01 = xv01 + xb01;
        f32x2 v23 = xv23 + xb23;
        v01 = __builtin_elementwise_max(v01, v01 * 0.2f);   // leaky_relu
        v23 = __builtin_elementwise_max(v23, v23 * 0.2f);
        f32x2 d2 = v01 * at01 + v23 * at23;
        float part = row16_sum(d2.x + d2.y);   // per-head logit (already ×log2e)
        float p = exp2f(part);                  // native v_exp_f32
        den += p;
        ac01 += p * xv01;
        ac23 += p * xv23;
    };

    int j = beg;
    for (; j + 4 <= end; j += 4) {
        int s0 = csr_src[j], s1 = csr_src[j + 1], s2 = csr_src[j + 2], s3 = csr_src[j + 3];
        uint2 w0 = *reinterpret_cast<const uint2*>(xbase + (size_t)(unsigned)s0);
        uint2 w1 = *reinterpret_cast<const uint2*>(xbase + (size_t)(unsigned)s1);
        uint2 w2 = *reinterpret_cast<const uint2*>(xbase + (size_t)(unsigned)s2);
        uint2 w3 = *reinterpret_cast<const uint2*>(xbase + (size_t)(unsigned)s3);
        edge(w0); edge(w1); edge(w2); edge(w3);
    }
    for (; j < end; ++j) {
        int s0 = csr_src[j];
        uint2 w0 = *reinterpret_cast<const uint2*>(xbase + (size_t)(unsigned)s0);
        edge(w0);
    }

    float inv = 1.f / (den + 1e-16f);
    float ax = ac01.x * inv, ay = ac01.y * inv, az = ac23.x * inv, aw = ac23.y * inv;

    if (LAYER == 1) {
        int c0 = lane * 4;
        float o0 = (ax + bias[c0 + 0]) * BN_SCALE * g[c0 + 0] + be[c0 + 0];
        float o1 = (ay + bias[c0 + 1]) * BN_SCALE * g[c0 + 1] + be[c0 + 1];
        float o2 = (az + bias[c0 + 2]) * BN_SCALE * g[c0 + 2] + be[c0 + 2];
        float o3 = (aw + bias[c0 + 3]) * BN_SCALE * g[c0 + 3] + be[c0 + 3];
        o0 = o0 > 0.f ? o0 : expm1f(o0);
        o1 = o1 > 0.f ? o1 : expm1f(o1);
        o2 = o2 > 0.f ? o2 : expm1f(o2);
        o3 = o3 > 0.f ? o3 : expm1f(o3);
        ushort4 o = { f2bf(o0), f2bf(o1), f2bf(o2), f2bf(o3) };
        *reinterpret_cast<ushort4*>((unsigned short*)outv + (size_t)wid * HC + lane * 4) = o;
    } else {
        // mean over heads: lanes l, l^16, l^32, l^48 hold the same channels
#pragma unroll
        for (int off = 16; off < 64; off <<= 1) {
            ax += __shfl_xor(ax, off);
            ay += __shfl_xor(ay, off);
            az += __shfl_xor(az, off);
            aw += __shfl_xor(aw, off);
        }
        int c0 = (lane & 15) * 4;
        float v0 = (ax * 0.25f + bias[c0 + 0]) * BN_SCALE * g[c0 + 0] + be[c0 + 0];
        float v1 = (ay * 0.25f + bias[c0 + 1]) * BN_SCALE * g[c0 + 1] + be[c0 + 1];
        float v2 = (az * 0.25f + bias[c0 + 2]) * BN_SCALE * g[c0 + 2] + be[c0 + 2];
        float v3 = (aw * 0.25f + bias[c0 + 3]) * BN_SCALE * g[c0 + 3] + be[c0 + 3];
        v0 = v0 > 0.f ? v0 : expm1f(v0);
        v1 = v1 > 0.f ? v1 : expm1f(v1);
        v2 = v2 > 0.f ? v2 : expm1f(v2);
        v3 = v3 > 0.f ? v3 : expm1f(v3);
        float dot = v0 * fcW[c0] + v1 * fcW[c0 + 1] + v2 * fcW[c0 + 2] + v3 * fcW[c0 + 3];
        dot = row16_sum(dot);
        if (lane == 0) ((float*)outv)[wid] = 1.f / (1.f + __expf(-(dot + fcb[0])));
    }
}

extern "C" void kernel_launch(void* const* d_in, const int* in_sizes, int n_in,
                              void* d_out, int out_size, void* d_ws, size_t ws_size,
                              hipStream_t stream) {
    const float* x    = (const float*)d_in[0];
    const int*   ei   = (const int*)d_in[1];
    const float* W1l  = (const float*)d_in[2];
    const float* W1r  = (const float*)d_in[3];
    const float* att1 = (const float*)d_in[4];
    const float* b1   = (const float*)d_in[5];
    const float* g1   = (const float*)d_in[6];
    const float* be1  = (const float*)d_in[7];
    const float* W2l  = (const float*)d_in[8];
    const float* W2r  = (const float*)d_in[9];
    const float* att2 = (const float*)d_in[10];
    const float* b2   = (const float*)d_in[11];
    const float* g2   = (const float*)d_in[12];
    const float* be2  = (const float*)d_in[13];
    const float* fcW  = (const float*)d_in[14];
    const float* fcb  = (const float*)d_in[15];
    float* out = (float*)d_out;

    // workspace carve-up (bf16 = ushort)
    unsigned short* xlr   = (unsigned short*)d_ws;                 // N*512
    unsigned short* h1_bf = xlr + (size_t)NNODES * NOUT;           // N*256
    unsigned short* Bf1   = h1_bf + (size_t)NNODES * 256;          // 128*512
    unsigned short* Bf2   = Bf1 + 128 * NOUT;                      // 256*512
    int* csr_src = (int*)(Bf2 + 256 * NOUT);                       // E2
    int* deg     = csr_src + E2;                                   // N  (also over-read pad)
    int* rowptr  = deg + NNODES;                                   // N+1
    int* cursor  = rowptr + NNODES + 1;                            // N
    int* bsum    = cursor + NNODES;                                // SCAN_B

    const int nodeBlocks = (NNODES * 64 + 255) / 256;

    hipMemsetAsync(deg, 0, NNODES * sizeof(int), stream);

    // K1: pack (W1, W2) || dst histogram
    k1_pack_hist<<<PACK_B + HIST_B, 256, 0, stream>>>(
        W1l, W1r, W2l, W2r, Bf1, Bf2, ei, deg);

    // K2: gemm layer-1 (direct f32 x) || scan1
    k2_gemm1_scan1<<<GEMM_B + SCAN_B, 256, 0, stream>>>(
        x, Bf1, xlr, NNODES, 128, deg, rowptr, bsum);

    // K3: bsum prefix + add-back
    k3_scan23<<<SCAN_B, 256, 0, stream>>>(bsum, rowptr, cursor);

    // K4: scatter into CSR (pre-scaled offsets)
    k4_scatter<<<HIST_B, 256, 0, stream>>>(ei, cursor, csr_src);

    // layer 1 aggregation + epilogue
    gat_node<1><<<nodeBlocks, 256, 0, stream>>>(xlr, att1, rowptr, csr_src,
                                                b1, g1, be1, nullptr, nullptr, h1_bf);

    // layer 2
    gemm_mfma<<<GEMM_B, 256, 0, stream>>>(h1_bf, Bf2, xlr, NNODES, 256);
    gat_node<2><<<nodeBlocks, 256, 0, stream>>>(xlr, att2, rowptr, csr_src,
                                                b2, g2, be2, fcW, fcb, out);
}

// Round 13
// 216.823 us; speedup vs baseline: 2.5591x; 1.0023x over previous
//
#include <hip/hip_runtime.h>
#include <math.h>

#define NNODES 50000
#define NEDGES 400000
#define E2 (NEDGES + NNODES)   // with self loops
#define HC 256                 // heads*channels per side
#define NOUT 512               // concat [Wl | Wr]
#define NF (NOUT / 16)         // 32 n-fragments
#define BN_SCALE 0.9999950000374997f   // 1/sqrt(1+1e-5)
#define LOG2E 1.4426950408889634f
#define SCAN_B ((NNODES + 255) / 256)  // 196
#define GEMM_B ((NNODES + 63) / 64)    // 782
#define HIST_B ((E2 + 255) / 256)      // 1758

typedef unsigned short ushortx8 __attribute__((ext_vector_type(8)));
typedef __bf16 bf16x8 __attribute__((ext_vector_type(8)));
typedef float f32x4 __attribute__((ext_vector_type(4)));
typedef float f32x2 __attribute__((ext_vector_type(2)));

__device__ inline unsigned short f2bf(float f) {
    unsigned u = __float_as_uint(f);
    u += 0x7fff + ((u >> 16) & 1);   // round to nearest even
    return (unsigned short)(u >> 16);
}

// VALU cross-lane add via DPP builtin (compiler handles DPP wait states;
// inline-asm DPP does NOT — round-11 corruption).
template <int CTRL>
__device__ __forceinline__ float dpp_add(float x) {
    int y = __builtin_amdgcn_update_dpp(0, __float_as_int(x), CTRL, 0xF, 0xF, true);
    return x + __int_as_float(y);
}
__device__ __forceinline__ float row16_sum(float x) {
    x = dpp_add<0xB1>(x);    // xor 1 (quad_perm [1,0,3,2])
    x = dpp_add<0x4E>(x);    // xor 2 (quad_perm [2,3,0,1])
    x = dpp_add<0x141>(x);   // row_half_mirror (xor 4)
    x = dpp_add<0x140>(x);   // row_mirror (xor 8)
    return x;
}

// ---------------- packing ----------------
#define XCVT_N (NNODES * 128 / 4)   // 1,600,000 float4s
#define B1_N (128 * NOUT)           // 65,536
#define B2_N (256 * NOUT)           // 131,072
#define PACK_B ((XCVT_N + B1_N + B2_N + 255) / 256)

__device__ __forceinline__ void prep_one(const float* __restrict__ Wl,
                                         const float* __restrict__ Wr,
                                         unsigned short* __restrict__ Bf, int id) {
    // Bf[(((kb*NF + nf)*64 + lane)*8 + j)] = B[kb*32 + (lane>>4)*8 + j][nf*16 + (lane&15)]
    int j    = id & 7;
    int lane = (id >> 3) & 63;
    int nf   = (id >> 9) & (NF - 1);
    int kb   = id >> 14;
    int k = kb * 32 + (lane >> 4) * 8 + j;
    int c = nf * 16 + (lane & 15);
    float v = (c < 256) ? Wl[k * 256 + c] : Wr[k * 256 + (c - 256)];
    Bf[id] = f2bf(v);
}

// K1: pack (x->bf16, W1/W2 fragment layout) || dst histogram
__global__ __launch_bounds__(256) void k1_pack_hist(
        const float* __restrict__ x,
        const float* __restrict__ W1l, const float* __restrict__ W1r,
        const float* __restrict__ W2l, const float* __restrict__ W2r,
        unsigned short* __restrict__ x_bf,
        unsigned short* __restrict__ Bf1, unsigned short* __restrict__ Bf2,
        const int* __restrict__ ei, int* __restrict__ deg) {
    int bid = blockIdx.x;
    if (bid < PACK_B) {
        int id = bid * 256 + threadIdx.x;
        if (id < XCVT_N) {
            float4 v = reinterpret_cast<const float4*>(x)[id];
            ushort4 o = { f2bf(v.x), f2bf(v.y), f2bf(v.z), f2bf(v.w) };
            reinterpret_cast<ushort4*>(x_bf)[id] = o;
        } else if (id < XCVT_N + B1_N) {
            prep_one(W1l, W1r, Bf1, id - XCVT_N);
        } else if (id < XCVT_N + B1_N + B2_N) {
            prep_one(W2l, W2r, Bf2, id - XCVT_N - B1_N);
        }
    } else {
        int i = (bid - PACK_B) * 256 + threadIdx.x;
        if (i < E2) {
            int d = (i < NEDGES) ? ei[NEDGES + i] : i - NEDGES;
            atomicAdd(&deg[d], 1);
        }
    }
}

// ---------------- GEMM body: C[M][512] = A[M][K] * B[K][512], bf16 A, bf16 C ----------------
__device__ __forceinline__ void gemm_body(int bx, int tid,
        const unsigned short* __restrict__ A, const unsigned short* __restrict__ Bf,
        unsigned short* __restrict__ C, int M, int K) {
    const int lane = tid & 63;
    const int w    = tid >> 6;          // col panel 0..3
    const int row0 = bx * 64;
    const int col0 = w * 128;
    const int lr = lane & 15, lg = lane >> 4;

    f32x4 acc[4][8] = {};
    const int nkb = K >> 5;
    for (int kb = 0; kb < nkb; ++kb) {
        bf16x8 af[4], bfr[8];
        const int kcol = kb * 32 + lg * 8;
#pragma unroll
        for (int i = 0; i < 4; ++i) {
            int r = row0 + i * 16 + lr;
            ushortx8 av = {};
            if (r < M)
                av = *reinterpret_cast<const ushortx8*>(A + (size_t)r * K + kcol);
            af[i] = __builtin_bit_cast(bf16x8, av);
        }
#pragma unroll
        for (int j = 0; j < 8; ++j) {
            int nf = (col0 >> 4) + j;
            ushortx8 bv = *reinterpret_cast<const ushortx8*>(
                Bf + (((size_t)(kb * NF + nf) * 64 + lane) << 3));
            bfr[j] = __builtin_bit_cast(bf16x8, bv);
        }
#pragma unroll
        for (int i = 0; i < 4; ++i)
#pragma unroll
            for (int j = 0; j < 8; ++j)
                acc[i][j] = __builtin_amdgcn_mfma_f32_16x16x32_bf16(
                    af[i], bfr[j], acc[i][j], 0, 0, 0);
    }
#pragma unroll
    for (int i = 0; i < 4; ++i) {
#pragma unroll
        for (int r = 0; r < 4; ++r) {
            int row = row0 + i * 16 + lg * 4 + r;
            if (row < M) {
#pragma unroll
                for (int j = 0; j < 8; ++j)
                    C[(size_t)row * NOUT + col0 + j * 16 + lr] = f2bf(acc[i][j][r]);
            }
        }
    }
}

// K2: gemm layer-1 (bf16 A) || block-local exclusive scan of deg
__global__ __launch_bounds__(256) void k2_gemm1_scan1(
        const unsigned short* __restrict__ A, const unsigned short* __restrict__ Bf,
        unsigned short* __restrict__ C, int M, int K,
        const int* __restrict__ deg, int* __restrict__ rowptr, int* __restrict__ bsum) {
    __shared__ int buf[256];
    if (blockIdx.x < GEMM_B) {
        gemm_body(blockIdx.x, threadIdx.x, A, Bf, C, M, K);
    } else {
        int bx = blockIdx.x - GEMM_B;
        int t = threadIdx.x;
        int i = bx * 256 + t;
        int v = (i < NNODES) ? deg[i] : 0;
        buf[t] = v;
        __syncthreads();
        for (int off = 1; off < 256; off <<= 1) {
            int u = (t >= off) ? buf[t - off] : 0;
            __syncthreads();
            buf[t] += u;
            __syncthreads();
        }
        if (i < NNODES) rowptr[i] = buf[t] - v;
        if (t == 255) bsum[bx] = buf[255];
    }
}

// K3: per-block recompute of bsum prefix + add-back
__global__ __launch_bounds__(256) void k3_scan23(
        const int* __restrict__ bsum, int* __restrict__ rowptr, int* __restrict__ cursor) {
    __shared__ int sbuf[256];
    int t = threadIdx.x;
    int v = (t < (int)blockIdx.x && t < SCAN_B) ? bsum[t] : 0;
    sbuf[t] = v;
    __syncthreads();
    for (int off = 128; off; off >>= 1) {
        if (t < off) sbuf[t] += sbuf[t + off];
        __syncthreads();
    }
    int base = sbuf[0];
    int i = blockIdx.x * 256 + t;
    if (i < NNODES) {
        int r = rowptr[i] + base;
        rowptr[i] = r;
        cursor[i] = r;
    }
    if (blockIdx.x == 0 && t == 0) rowptr[NNODES] = E2;
}

// K4: scatter src into dst-grouped order; stores PRE-SCALED row offset (s*NOUT)
__global__ __launch_bounds__(256) void k4_scatter(
        const int* __restrict__ ei, int* __restrict__ cursor, int* __restrict__ csr_src) {
    int i = blockIdx.x * blockDim.x + threadIdx.x;
    if (i >= E2) return;
    int s, d;
    if (i < NEDGES) { s = ei[i]; d = ei[NEDGES + i]; }
    else            { s = i - NEDGES; d = s; }
    int slot = atomicAdd(&cursor[d], 1);
    csr_src[slot] = s * NOUT;
}

// standalone GEMM (layer 2, bf16 A)
__global__ __launch_bounds__(256) void gemm_mfma(
        const unsigned short* __restrict__ A, const unsigned short* __restrict__ Bf,
        unsigned short* __restrict__ C, int M, int K) {
    gemm_body(blockIdx.x, threadIdx.x, A, Bf, C, M, K);
}

// ---------------- fused per-node GAT: dual accumulator sets, DPP reduce, exp2 ----------
// xlr[N][512] bf16: cols 0..255 = xl (messages), 256..511 = xr (dest)
// csr_src holds pre-scaled row offsets (src*NOUT).
template <int LAYER>
__global__ __launch_bounds__(256) void gat_node(
        const unsigned short* __restrict__ xlr,
        const float* __restrict__ att, const int* __restrict__ rowptr,
        const int* __restrict__ csr_src,
        const float* __restrict__ bias, const float* __restrict__ g,
        const float* __restrict__ be,
        const float* __restrict__ fcW, const float* __restrict__ fcb,
        void* __restrict__ outv) {
    int wid  = (blockIdx.x * blockDim.x + threadIdx.x) >> 6;   // node id
    int lane = threadIdx.x & 63;
    if (wid >= NNODES) return;

    f32x2 xb01, xb23, at01, at23;
    {
        uint2 wv = *reinterpret_cast<const uint2*>(xlr + (size_t)wid * NOUT + 256 + lane * 4);
        xb01.x = __uint_as_float(wv.x << 16);
        xb01.y = __uint_as_float(wv.x & 0xffff0000u);
        xb23.x = __uint_as_float(wv.y << 16);
        xb23.y = __uint_as_float(wv.y & 0xffff0000u);
        float4 a = *reinterpret_cast<const float4*>(att + lane * 4);
        at01.x = a.x * LOG2E; at01.y = a.y * LOG2E;   // exp(e) == exp2(e*log2e)
        at23.x = a.z * LOG2E; at23.y = a.w * LOG2E;
    }
    const int beg = rowptr[wid];
    const int end = rowptr[wid + 1];
    const unsigned short* __restrict__ xbase = xlr + lane * 4;

    // dual accumulator sets: halves the serial accumulation chain across edges
    float den0 = 0.f, den1 = 0.f;
    f32x2 a001 = {0.f, 0.f}, a023 = {0.f, 0.f};
    f32x2 a101 = {0.f, 0.f}, a123 = {0.f, 0.f};

    auto edge = [&](uint2 wv, float& den, f32x2& acA, f32x2& acB) {
        f32x2 xv01, xv23;
        xv01.x = __uint_as_float(wv.x << 16);
        xv01.y = __uint_as_float(wv.x & 0xffff0000u);
        xv23.x = __uint_as_float(wv.y << 16);
        xv23.y = __uint_as_float(wv.y & 0xffff0000u);
        f32x2 v01 = xv01 + xb01;
        f32x2 v23 = xv23 + xb23;
        v01 = __builtin_elementwise_max(v01, v01 * 0.2f);   // leaky_relu
        v23 = __builtin_elementwise_max(v23, v23 * 0.2f);
        f32x2 d2 = v01 * at01 + v23 * at23;
        float part = row16_sum(d2.x + d2.y);   // per-head logit (already ×log2e)
        float p = exp2f(part);                  // native v_exp_f32
        den += p;
        acA += p * xv01;
        acB += p * xv23;
    };

    int j = beg;
    for (; j + 4 <= end; j += 4) {
        int s0 = csr_src[j], s1 = csr_src[j + 1], s2 = csr_src[j + 2], s3 = csr_src[j + 3];
        uint2 w0 = *reinterpret_cast<const uint2*>(xbase + (size_t)(unsigned)s0);
        uint2 w1 = *reinterpret_cast<const uint2*>(xbase + (size_t)(unsigned)s1);
        uint2 w2 = *reinterpret_cast<const uint2*>(xbase + (size_t)(unsigned)s2);
        uint2 w3 = *reinterpret_cast<const uint2*>(xbase + (size_t)(unsigned)s3);
        edge(w0, den0, a001, a023);
        edge(w1, den1, a101, a123);
        edge(w2, den0, a001, a023);
        edge(w3, den1, a101, a123);
    }
    for (; j < end; ++j) {
        int s0 = csr_src[j];
        uint2 w0 = *reinterpret_cast<const uint2*>(xbase + (size_t)(unsigned)s0);
        edge(w0, den0, a001, a023);
    }
    float den = den0 + den1;
    f32x2 ac01 = a001 + a101;
    f32x2 ac23 = a023 + a123;

    float inv = 1.f / (den + 1e-16f);
    float ax = ac01.x * inv, ay = ac01.y * inv, az = ac23.x * inv, aw = ac23.y * inv;

    if (LAYER == 1) {
        int c0 = lane * 4;
        float o0 = (ax + bias[c0 + 0]) * BN_SCALE * g[c0 + 0] + be[c0 + 0];
        float o1 = (ay + bias[c0 + 1]) * BN_SCALE * g[c0 + 1] + be[c0 + 1];
        float o2 = (az + bias[c0 + 2]) * BN_SCALE * g[c0 + 2] + be[c0 + 2];
        float o3 = (aw + bias[c0 + 3]) * BN_SCALE * g[c0 + 3] + be[c0 + 3];
        o0 = o0 > 0.f ? o0 : expm1f(o0);
        o1 = o1 > 0.f ? o1 : expm1f(o1);
        o2 = o2 > 0.f ? o2 : expm1f(o2);
        o3 = o3 > 0.f ? o3 : expm1f(o3);
        ushort4 o = { f2bf(o0), f2bf(o1), f2bf(o2), f2bf(o3) };
        *reinterpret_cast<ushort4*>((unsigned short*)outv + (size_t)wid * HC + lane * 4) = o;
    } else {
        // mean over heads: lanes l, l^16, l^32, l^48 hold the same channels
#pragma unroll
        for (int off = 16; off < 64; off <<= 1) {
            ax += __shfl_xor(ax, off);
            ay += __shfl_xor(ay, off);
            az += __shfl_xor(az, off);
            aw += __shfl_xor(aw, off);
        }
        int c0 = (lane & 15) * 4;
        float v0 = (ax * 0.25f + bias[c0 + 0]) * BN_SCALE * g[c0 + 0] + be[c0 + 0];
        float v1 = (ay * 0.25f + bias[c0 + 1]) * BN_SCALE * g[c0 + 1] + be[c0 + 1];
        float v2 = (az * 0.25f + bias[c0 + 2]) * BN_SCALE * g[c0 + 2] + be[c0 + 2];
        float v3 = (aw * 0.25f + bias[c0 + 3]) * BN_SCALE * g[c0 + 3] + be[c0 + 3];
        v0 = v0 > 0.f ? v0 : expm1f(v0);
        v1 = v1 > 0.f ? v1 : expm1f(v1);
        v2 = v2 > 0.f ? v2 : expm1f(v2);
        v3 = v3 > 0.f ? v3 : expm1f(v3);
        float dot = v0 * fcW[c0] + v1 * fcW[c0 + 1] + v2 * fcW[c0 + 2] + v3 * fcW[c0 + 3];
        dot = row16_sum(dot);
        if (lane == 0) ((float*)outv)[wid] = 1.f / (1.f + __expf(-(dot + fcb[0])));
    }
}

extern "C" void kernel_launch(void* const* d_in, const int* in_sizes, int n_in,
                              void* d_out, int out_size, void* d_ws, size_t ws_size,
                              hipStream_t stream) {
    const float* x    = (const float*)d_in[0];
    const int*   ei   = (const int*)d_in[1];
    const float* W1l  = (const float*)d_in[2];
    const float* W1r  = (const float*)d_in[3];
    const float* att1 = (const float*)d_in[4];
    const float* b1   = (const float*)d_in[5];
    const float* g1   = (const float*)d_in[6];
    const float* be1  = (const float*)d_in[7];
    const float* W2l  = (const float*)d_in[8];
    const float* W2r  = (const float*)d_in[9];
    const float* att2 = (const float*)d_in[10];
    const float* b2   = (const float*)d_in[11];
    const float* g2   = (const float*)d_in[12];
    const float* be2  = (const float*)d_in[13];
    const float* fcW  = (const float*)d_in[14];
    const float* fcb  = (const float*)d_in[15];
    float* out = (float*)d_out;

    // workspace carve-up (bf16 = ushort)
    unsigned short* xlr   = (unsigned short*)d_ws;                 // N*512
    unsigned short* x_bf  = xlr + (size_t)NNODES * NOUT;           // N*128
    unsigned short* h1_bf = x_bf + (size_t)NNODES * 128;           // N*256
    unsigned short* Bf1   = h1_bf + (size_t)NNODES * 256;          // 128*512
    unsigned short* Bf2   = Bf1 + 128 * NOUT;                      // 256*512
    int* csr_src = (int*)(Bf2 + 256 * NOUT);                       // E2
    int* deg     = csr_src + E2;                                   // N  (also over-read pad)
    int* rowptr  = deg + NNODES;                                   // N+1
    int* cursor  = rowptr + NNODES + 1;                            // N
    int* bsum    = cursor + NNODES;                                // SCAN_B

    const int nodeBlocks = (NNODES * 64 + 255) / 256;

    hipMemsetAsync(deg, 0, NNODES * sizeof(int), stream);

    // K1: pack (x, W1, W2) || dst histogram
    k1_pack_hist<<<PACK_B + HIST_B, 256, 0, stream>>>(
        x, W1l, W1r, W2l, W2r, x_bf, Bf1, Bf2, ei, deg);

    // K2: gemm layer-1 (bf16 A) || scan1
    k2_gemm1_scan1<<<GEMM_B + SCAN_B, 256, 0, stream>>>(
        x_bf, Bf1, xlr, NNODES, 128, deg, rowptr, bsum);

    // K3: bsum prefix + add-back
    k3_scan23<<<SCAN_B, 256, 0, stream>>>(bsum, rowptr, cursor);

    // K4: scatter into CSR (pre-scaled offsets)
    k4_scatter<<<HIST_B, 256, 0, stream>>>(ei, cursor, csr_src);

    // layer 1 aggregation + epilogue
    gat_node<1><<<nodeBlocks, 256, 0, stream>>>(xlr, att1, rowptr, csr_src,
                                                b1, g1, be1, nullptr, nullptr, h1_bf);

    // layer 2
    gemm_mfma<<<GEMM_B, 256, 0, stream>>>(h1_bf, Bf2, xlr, NNODES, 256);
    gat_node<2><<<nodeBlocks, 256, 0, stream>>>(xlr, att2, rowptr, csr_src,
                                                b2, g2, be2, fcW, fcb, out);
}

// Round 14
// 209.005 us; speedup vs baseline: 2.6548x; 1.0374x over previous
//
#include <hip/hip_runtime.h>
#include <math.h>

#define NNODES 50000
#define NEDGES 400000
#define E2 (NEDGES + NNODES)   // with self loops
#define HC 256                 // heads*channels per side
#define NOUT 512               // concat [Wl | Wr]
#define NF (NOUT / 16)         // 32 n-fragments
#define BN_SCALE 0.9999950000374997f   // 1/sqrt(1+1e-5)
#define LOG2E 1.4426950408889634f
#define SCAN_B ((NNODES + 255) / 256)  // 196
#define GEMM_B ((NNODES + 63) / 64)    // 782
#define HIST_B ((E2 + 255) / 256)      // 1758

typedef unsigned short ushortx8 __attribute__((ext_vector_type(8)));
typedef __bf16 bf16x8 __attribute__((ext_vector_type(8)));
typedef float f32x4 __attribute__((ext_vector_type(4)));
typedef float f32x2 __attribute__((ext_vector_type(2)));

__device__ inline unsigned short f2bf(float f) {
    unsigned u = __float_as_uint(f);
    u += 0x7fff + ((u >> 16) & 1);   // round to nearest even
    return (unsigned short)(u >> 16);
}

// VALU cross-lane add via DPP builtin (compiler handles DPP wait states;
// inline-asm DPP does NOT — round-11 corruption).
template <int CTRL>
__device__ __forceinline__ float dpp_add(float x) {
    int y = __builtin_amdgcn_update_dpp(0, __float_as_int(x), CTRL, 0xF, 0xF, true);
    return x + __int_as_float(y);
}
__device__ __forceinline__ float row16_sum(float x) {
    x = dpp_add<0xB1>(x);    // xor 1 (quad_perm [1,0,3,2])
    x = dpp_add<0x4E>(x);    // xor 2 (quad_perm [2,3,0,1])
    x = dpp_add<0x141>(x);   // row_half_mirror (xor 4)
    x = dpp_add<0x140>(x);   // row_mirror (xor 8)
    return x;
}

// ---------------- packing ----------------
#define XCVT_N (NNODES * 128 / 4)   // 1,600,000 float4s
#define B1_N (128 * NOUT)           // 65,536
#define B2_N (256 * NOUT)           // 131,072
#define PACK_B ((XCVT_N + B1_N + B2_N + 255) / 256)

__device__ __forceinline__ void prep_one(const float* __restrict__ Wl,
                                         const float* __restrict__ Wr,
                                         unsigned short* __restrict__ Bf, int id) {
    // Bf[(((kb*NF + nf)*64 + lane)*8 + j)] = B[kb*32 + (lane>>4)*8 + j][nf*16 + (lane&15)]
    int j    = id & 7;
    int lane = (id >> 3) & 63;
    int nf   = (id >> 9) & (NF - 1);
    int kb   = id >> 14;
    int k = kb * 32 + (lane >> 4) * 8 + j;
    int c = nf * 16 + (lane & 15);
    float v = (c < 256) ? Wl[k * 256 + c] : Wr[k * 256 + (c - 256)];
    Bf[id] = f2bf(v);
}

// K1: pack (x->bf16, W1/W2 fragment layout) || dst histogram
__global__ __launch_bounds__(256) void k1_pack_hist(
        const float* __restrict__ x,
        const float* __restrict__ W1l, const float* __restrict__ W1r,
        const float* __restrict__ W2l, const float* __restrict__ W2r,
        unsigned short* __restrict__ x_bf,
        unsigned short* __restrict__ Bf1, unsigned short* __restrict__ Bf2,
        const int* __restrict__ ei, int* __restrict__ deg) {
    int bid = blockIdx.x;
    if (bid < PACK_B) {
        int id = bid * 256 + threadIdx.x;
        if (id < XCVT_N) {
            float4 v = reinterpret_cast<const float4*>(x)[id];
            ushort4 o = { f2bf(v.x), f2bf(v.y), f2bf(v.z), f2bf(v.w) };
            reinterpret_cast<ushort4*>(x_bf)[id] = o;
        } else if (id < XCVT_N + B1_N) {
            prep_one(W1l, W1r, Bf1, id - XCVT_N);
        } else if (id < XCVT_N + B1_N + B2_N) {
            prep_one(W2l, W2r, Bf2, id - XCVT_N - B1_N);
        }
    } else {
        int i = (bid - PACK_B) * 256 + threadIdx.x;
        if (i < E2) {
            int d = (i < NEDGES) ? ei[NEDGES + i] : i - NEDGES;
            atomicAdd(&deg[d], 1);
        }
    }
}

// ---------------- GEMM body: C[M][512] = A[M][K] * B[K][512], bf16 A, bf16 C ----------------
__device__ __forceinline__ void gemm_body(int bx, int tid,
        const unsigned short* __restrict__ A, const unsigned short* __restrict__ Bf,
        unsigned short* __restrict__ C, int M, int K) {
    const int lane = tid & 63;
    const int w    = tid >> 6;          // col panel 0..3
    const int row0 = bx * 64;
    const int col0 = w * 128;
    const int lr = lane & 15, lg = lane >> 4;

    f32x4 acc[4][8] = {};
    const int nkb = K >> 5;
    for (int kb = 0; kb < nkb; ++kb) {
        bf16x8 af[4], bfr[8];
        const int kcol = kb * 32 + lg * 8;
#pragma unroll
        for (int i = 0; i < 4; ++i) {
            int r = row0 + i * 16 + lr;
            ushortx8 av = {};
            if (r < M)
                av = *reinterpret_cast<const ushortx8*>(A + (size_t)r * K + kcol);
            af[i] = __builtin_bit_cast(bf16x8, av);
        }
#pragma unroll
        for (int j = 0; j < 8; ++j) {
            int nf = (col0 >> 4) + j;
            ushortx8 bv = *reinterpret_cast<const ushortx8*>(
                Bf + (((size_t)(kb * NF + nf) * 64 + lane) << 3));
            bfr[j] = __builtin_bit_cast(bf16x8, bv);
        }
#pragma unroll
        for (int i = 0; i < 4; ++i)
#pragma unroll
            for (int j = 0; j < 8; ++j)
                acc[i][j] = __builtin_amdgcn_mfma_f32_16x16x32_bf16(
                    af[i], bfr[j], acc[i][j], 0, 0, 0);
    }
#pragma unroll
    for (int i = 0; i < 4; ++i) {
#pragma unroll
        for (int r = 0; r < 4; ++r) {
            int row = row0 + i * 16 + lg * 4 + r;
            if (row < M) {
#pragma unroll
                for (int j = 0; j < 8; ++j)
                    C[(size_t)row * NOUT + col0 + j * 16 + lr] = f2bf(acc[i][j][r]);
            }
        }
    }
}

// K2: gemm layer-1 (bf16 A) || block-local exclusive scan of deg
__global__ __launch_bounds__(256) void k2_gemm1_scan1(
        const unsigned short* __restrict__ A, const unsigned short* __restrict__ Bf,
        unsigned short* __restrict__ C, int M, int K,
        const int* __restrict__ deg, int* __restrict__ rowptr, int* __restrict__ bsum) {
    __shared__ int buf[256];
    if (blockIdx.x < GEMM_B) {
        gemm_body(blockIdx.x, threadIdx.x, A, Bf, C, M, K);
    } else {
        int bx = blockIdx.x - GEMM_B;
        int t = threadIdx.x;
        int i = bx * 256 + t;
        int v = (i < NNODES) ? deg[i] : 0;
        buf[t] = v;
        __syncthreads();
        for (int off = 1; off < 256; off <<= 1) {
            int u = (t >= off) ? buf[t - off] : 0;
            __syncthreads();
            buf[t] += u;
            __syncthreads();
        }
        if (i < NNODES) rowptr[i] = buf[t] - v;
        if (t == 255) bsum[bx] = buf[255];
    }
}

// K3: per-block recompute of bsum prefix + add-back
__global__ __launch_bounds__(256) void k3_scan23(
        const int* __restrict__ bsum, int* __restrict__ rowptr, int* __restrict__ cursor) {
    __shared__ int sbuf[256];
    int t = threadIdx.x;
    int v = (t < (int)blockIdx.x && t < SCAN_B) ? bsum[t] : 0;
    sbuf[t] = v;
    __syncthreads();
    for (int off = 128; off; off >>= 1) {
        if (t < off) sbuf[t] += sbuf[t + off];
        __syncthreads();
    }
    int base = sbuf[0];
    int i = blockIdx.x * 256 + t;
    if (i < NNODES) {
        int r = rowptr[i] + base;
        rowptr[i] = r;
        cursor[i] = r;
    }
    if (blockIdx.x == 0 && t == 0) rowptr[NNODES] = E2;
}

// K4: scatter src into dst-grouped order; stores PRE-SCALED row offset (s*NOUT)
__global__ __launch_bounds__(256) void k4_scatter(
        const int* __restrict__ ei, int* __restrict__ cursor, int* __restrict__ csr_src) {
    int i = blockIdx.x * blockDim.x + threadIdx.x;
    if (i >= E2) return;
    int s, d;
    if (i < NEDGES) { s = ei[i]; d = ei[NEDGES + i]; }
    else            { s = i - NEDGES; d = s; }
    int slot = atomicAdd(&cursor[d], 1);
    csr_src[slot] = s * NOUT;
}

// standalone GEMM (layer 2, bf16 A)
__global__ __launch_bounds__(256) void gemm_mfma(
        const unsigned short* __restrict__ A, const unsigned short* __restrict__ Bf,
        unsigned short* __restrict__ C, int M, int K) {
    gemm_body(blockIdx.x, threadIdx.x, A, Bf, C, M, K);
}

// ---------------- fused per-node GAT: 4 ch/lane, DPP reduce, native exp2, 4-edge unroll ----
// xlr[N][512] bf16: cols 0..255 = xl (messages), 256..511 = xr (dest)
// csr_src holds pre-scaled row offsets (src*NOUT).
template <int LAYER>
__global__ __launch_bounds__(256) void gat_node(
        const unsigned short* __restrict__ xlr,
        const float* __restrict__ att, const int* __restrict__ rowptr,
        const int* __restrict__ csr_src,
        const float* __restrict__ bias, const float* __restrict__ g,
        const float* __restrict__ be,
        const float* __restrict__ fcW, const float* __restrict__ fcb,
        void* __restrict__ outv) {
    int wid  = (blockIdx.x * blockDim.x + threadIdx.x) >> 6;   // node id
    int lane = threadIdx.x & 63;
    if (wid >= NNODES) return;

    f32x2 xb01, xb23, at01, at23;
    {
        uint2 wv = *reinterpret_cast<const uint2*>(xlr + (size_t)wid * NOUT + 256 + lane * 4);
        xb01.x = __uint_as_float(wv.x << 16);
        xb01.y = __uint_as_float(wv.x & 0xffff0000u);
        xb23.x = __uint_as_float(wv.y << 16);
        xb23.y = __uint_as_float(wv.y & 0xffff0000u);
        float4 a = *reinterpret_cast<const float4*>(att + lane * 4);
        at01.x = a.x * LOG2E; at01.y = a.y * LOG2E;   // exp(e) == exp2(e*log2e)
        at23.x = a.z * LOG2E; at23.y = a.w * LOG2E;
    }
    const int beg = rowptr[wid];
    const int end = rowptr[wid + 1];
    const unsigned short* __restrict__ xbase = xlr + lane * 4;

    float den = 0.f;
    f32x2 ac01 = {0.f, 0.f}, ac23 = {0.f, 0.f};

    auto edge = [&](uint2 wv) {
        f32x2 xv01, xv23;
        xv01.x = __uint_as_float(wv.x << 16);
        xv01.y = __uint_as_float(wv.x & 0xffff0000u);
        xv23.x = __uint_as_float(wv.y << 16);
        xv23.y = __uint_as_float(wv.y & 0xffff0000u);
        f32x2 v01 = xv01 + xb01;
        f32x2 v23 = xv23 + xb23;
        v01 = __builtin_elementwise_max(v01, v01 * 0.2f);   // leaky_relu
        v23 = __builtin_elementwise_max(v23, v23 * 0.2f);
        f32x2 d2 = v01 * at01 + v23 * at23;
        float part = row16_sum(d2.x + d2.y);        // per-head logit (already ×log2e)
        float p = __builtin_amdgcn_exp2f(part);     // raw v_exp_f32
        den += p;
        ac01 += p * xv01;
        ac23 += p * xv23;
    };

    int j = beg;
    for (; j + 4 <= end; j += 4) {
        int s0 = csr_src[j], s1 = csr_src[j + 1], s2 = csr_src[j + 2], s3 = csr_src[j + 3];
        uint2 w0 = *reinterpret_cast<const uint2*>(xbase + (size_t)(unsigned)s0);
        uint2 w1 = *reinterpret_cast<const uint2*>(xbase + (size_t)(unsigned)s1);
        uint2 w2 = *reinterpret_cast<const uint2*>(xbase + (size_t)(unsigned)s2);
        uint2 w3 = *reinterpret_cast<const uint2*>(xbase + (size_t)(unsigned)s3);
        edge(w0); edge(w1); edge(w2); edge(w3);
    }
    for (; j < end; ++j) {
        int s0 = csr_src[j];
        uint2 w0 = *reinterpret_cast<const uint2*>(xbase + (size_t)(unsigned)s0);
        edge(w0);
    }

    float inv = 1.f / (den + 1e-16f);
    float ax = ac01.x * inv, ay = ac01.y * inv, az = ac23.x * inv, aw = ac23.y * inv;

    if (LAYER == 1) {
        int c0 = lane * 4;
        float o0 = (ax + bias[c0 + 0]) * BN_SCALE * g[c0 + 0] + be[c0 + 0];
        float o1 = (ay + bias[c0 + 1]) * BN_SCALE * g[c0 + 1] + be[c0 + 1];
        float o2 = (az + bias[c0 + 2]) * BN_SCALE * g[c0 + 2] + be[c0 + 2];
        float o3 = (aw + bias[c0 + 3]) * BN_SCALE * g[c0 + 3] + be[c0 + 3];
        o0 = o0 > 0.f ? o0 : expm1f(o0);
        o1 = o1 > 0.f ? o1 : expm1f(o1);
        o2 = o2 > 0.f ? o2 : expm1f(o2);
        o3 = o3 > 0.f ? o3 : expm1f(o3);
        ushort4 o = { f2bf(o0), f2bf(o1), f2bf(o2), f2bf(o3) };
        *reinterpret_cast<ushort4*>((unsigned short*)outv + (size_t)wid * HC + lane * 4) = o;
    } else {
        // mean over heads: lanes l, l^16, l^32, l^48 hold the same channels
#pragma unroll
        for (int off = 16; off < 64; off <<= 1) {
            ax += __shfl_xor(ax, off);
            ay += __shfl_xor(ay, off);
            az += __shfl_xor(az, off);
            aw += __shfl_xor(aw, off);
        }
        int c0 = (lane & 15) * 4;
        float v0 = (ax * 0.25f + bias[c0 + 0]) * BN_SCALE * g[c0 + 0] + be[c0 + 0];
        float v1 = (ay * 0.25f + bias[c0 + 1]) * BN_SCALE * g[c0 + 1] + be[c0 + 1];
        float v2 = (az * 0.25f + bias[c0 + 2]) * BN_SCALE * g[c0 + 2] + be[c0 + 2];
        float v3 = (aw * 0.25f + bias[c0 + 3]) * BN_SCALE * g[c0 + 3] + be[c0 + 3];
        v0 = v0 > 0.f ? v0 : expm1f(v0);
        v1 = v1 > 0.f ? v1 : expm1f(v1);
        v2 = v2 > 0.f ? v2 : expm1f(v2);
        v3 = v3 > 0.f ? v3 : expm1f(v3);
        float dot = v0 * fcW[c0] + v1 * fcW[c0 + 1] + v2 * fcW[c0 + 2] + v3 * fcW[c0 + 3];
        dot = row16_sum(dot);
        if (lane == 0) ((float*)outv)[wid] = 1.f / (1.f + __expf(-(dot + fcb[0])));
    }
}

extern "C" void kernel_launch(void* const* d_in, const int* in_sizes, int n_in,
                              void* d_out, int out_size, void* d_ws, size_t ws_size,
                              hipStream_t stream) {
    const float* x    = (const float*)d_in[0];
    const int*   ei   = (const int*)d_in[1];
    const float* W1l  = (const float*)d_in[2];
    const float* W1r  = (const float*)d_in[3];
    const float* att1 = (const float*)d_in[4];
    const float* b1   = (const float*)d_in[5];
    const float* g1   = (const float*)d_in[6];
    const float* be1  = (const float*)d_in[7];
    const float* W2l  = (const float*)d_in[8];
    const float* W2r  = (const float*)d_in[9];
    const float* att2 = (const float*)d_in[10];
    const float* b2   = (const float*)d_in[11];
    const float* g2   = (const float*)d_in[12];
    const float* be2  = (const float*)d_in[13];
    const float* fcW  = (const float*)d_in[14];
    const float* fcb  = (const float*)d_in[15];
    float* out = (float*)d_out;

    // workspace carve-up (bf16 = ushort)
    unsigned short* xlr   = (unsigned short*)d_ws;                 // N*512
    unsigned short* x_bf  = xlr + (size_t)NNODES * NOUT;           // N*128
    unsigned short* h1_bf = x_bf + (size_t)NNODES * 128;           // N*256
    unsigned short* Bf1   = h1_bf + (size_t)NNODES * 256;          // 128*512
    unsigned short* Bf2   = Bf1 + 128 * NOUT;                      // 256*512
    int* csr_src = (int*)(Bf2 + 256 * NOUT);                       // E2
    int* deg     = csr_src + E2;                                   // N  (also over-read pad)
    int* rowptr  = deg + NNODES;                                   // N+1
    int* cursor  = rowptr + NNODES + 1;                            // N
    int* bsum    = cursor + NNODES;                                // SCAN_B

    const int nodeBlocks = (NNODES * 64 + 255) / 256;

    hipMemsetAsync(deg, 0, NNODES * sizeof(int), stream);

    // K1: pack (x, W1, W2) || dst histogram
    k1_pack_hist<<<PACK_B + HIST_B, 256, 0, stream>>>(
        x, W1l, W1r, W2l, W2r, x_bf, Bf1, Bf2, ei, deg);

    // K2: gemm layer-1 (bf16 A) || scan1
    k2_gemm1_scan1<<<GEMM_B + SCAN_B, 256, 0, stream>>>(
        x_bf, Bf1, xlr, NNODES, 128, deg, rowptr, bsum);

    // K3: bsum prefix + add-back
    k3_scan23<<<SCAN_B, 256, 0, stream>>>(bsum, rowptr, cursor);

    // K4: scatter into CSR (pre-scaled offsets)
    k4_scatter<<<HIST_B, 256, 0, stream>>>(ei, cursor, csr_src);

    // layer 1 aggregation + epilogue
    gat_node<1><<<nodeBlocks, 256, 0, stream>>>(xlr, att1, rowptr, csr_src,
                                                b1, g1, be1, nullptr, nullptr, h1_bf);

    // layer 2
    gemm_mfma<<<GEMM_B, 256, 0, stream>>>(h1_bf, Bf2, xlr, NNODES, 256);
    gat_node<2><<<nodeBlocks, 256, 0, stream>>>(xlr, att2, rowptr, csr_src,
                                                b2, g2, be2, fcW, fcb, out);
}